// Round 6
// baseline (234.879 us; speedup 1.0000x reference)
//
#include <hip/hip_runtime.h>
#include <hip/hip_bf16.h>

// A=8, B=32768, S=128, AD=16, H=64, NH=4, D=16
#define A_N 8
#define B_N 32768
#define S_N 128
#define AD_N 16

typedef __attribute__((ext_vector_type(8))) short short8;
typedef __attribute__((ext_vector_type(4))) float floatx4;
typedef __attribute__((ext_vector_type(4))) int intx4;

#define MFMA16(a, b, c) __builtin_amdgcn_mfma_f32_16x16x32_bf16(a, b, c, 0, 0, 0)
#define SBAR() __builtin_amdgcn_sched_barrier(0)

__device__ __forceinline__ short f2bf(float f) {
    __hip_bfloat16 h = __float2bfloat16(f);
    return *reinterpret_cast<short*>(&h);
}
// pack 2 f32 -> u32 of 2 bf16 (low short = first arg)
__device__ __forceinline__ int pk(float a, float b) {
    __hip_bfloat162 p = __float22bfloat162_rn(make_float2(a, b));
    return *reinterpret_cast<int*>(&p);
}
__device__ __forceinline__ short8 mk8(int a, int b, int c, int d) {
    intx4 v = {a, b, c, d};
    return *reinterpret_cast<short8*>(&v);
}
__device__ __forceinline__ void pk2(short8& r, int i, float a, float b) {
    __hip_bfloat162 p = __float22bfloat162_rn(make_float2(a, b));
    short2 s = *reinterpret_cast<short2*>(&p);
    r[i] = s.x; r[i + 1] = s.y;
}
__device__ __forceinline__ short8 cvt8(float4 x0, float4 x1) {
    short8 r;
    pk2(r, 0, x0.x, x0.y); pk2(r, 2, x0.z, x0.w);
    pk2(r, 4, x1.x, x1.y); pk2(r, 6, x1.z, x1.w);
    return r;
}

// k-permutation for the phase-2/4 weight operands: physical k position p
// (p = s*32 + lq*8 + e) holds logical channel ch = 32s + 16(e>>2) + 4lq + (e&3),
// so the activation-side fragment is a pure within-lane repack of the previous
// MFMA's accumulator (lane (lq,ln) holds channels nt*16+4lq+i).
__device__ __forceinline__ int chperm(int p) {
    return 32 * (p >> 5) + 16 * ((p & 7) >> 2) + 4 * ((p >> 3) & 3) + (p & 3);
}

// ---- weight prep into d_ws: FRAGMENT-MAJOR bf16 ----
// Each 16B MFMA weight fragment (s, lq, ch) stored contiguously at short
// offset ((s*4+lq)*64 + ch)*8, element e = W[perm(s*32+lq*8+e)][ch].
// shorts: We[K=160]@0 (k identity; k=144 holds be) | Ws[K=128]@10240 (bias via VALU)
//         Wk[K=64]@18432 | Wsel@22528 | Wv@26624 (chperm) | W1[K=128]@30720 (chperm)
#define OFF_Ws   10240
#define OFF_Wk   18432
#define OFF_Wsel 22528
#define OFF_Wv   26624
#define OFF_W1   30720
#define W_TOTAL  38912   // shorts = 77824 B = 76 x 1 KiB chunks

__global__ void prep_weights(const float* __restrict__ Ws, const float* __restrict__ We,
                             const float* __restrict__ be,
                             const float* __restrict__ Wk, const float* __restrict__ Wsel,
                             const float* __restrict__ Wv, const float* __restrict__ W1,
                             short* __restrict__ w) {
    int idx = blockIdx.x * 256 + threadIdx.x;
    if (idx >= W_TOTAL) return;
    float v = 0.f;
    int i, base;
    if (idx < OFF_Ws)        { i = idx;            base = 0; }
    else if (idx < OFF_Wk)   { i = idx - OFF_Ws;   base = 1; }
    else if (idx < OFF_Wsel) { i = idx - OFF_Wk;   base = 2; }
    else if (idx < OFF_Wv)   { i = idx - OFF_Wsel; base = 3; }
    else if (idx < OFF_W1)   { i = idx - OFF_Wv;   base = 4; }
    else                     { i = idx - OFF_W1;   base = 5; }
    const int e   = i & 7;
    const int f   = i >> 3;
    const int ch  = f & 63;
    const int slq = f >> 6;
    const int p   = (slq >> 2) * 32 + (slq & 3) * 8 + e;
    if (base == 0)      v = (p < 144) ? We[p * 64 + ch] : (p == 144 ? be[ch] : 0.f);
    else if (base == 1) v = Ws[p * 64 + ch];
    else if (base == 2) v = Wk[(ch >> 4) * 1024 + chperm(p) * 16 + (ch & 15)];
    else if (base == 3) v = Wsel[(ch >> 4) * 1024 + chperm(p) * 16 + (ch & 15)];
    else if (base == 4) v = Wv[(ch >> 4) * 1024 + chperm(p) * 16 + (ch & 15)];
    else                v = W1[chperm(p) * 64 + ch];
    w[idx] = f2bf(v);
}

#define PAIRS 4   // 2 tiles/pair, 32 batches/pair/block, 128/block, grid = 256

// v6: LDS-traffic halving. Rounds 4->5 showed occupancy doubling changes
// nothing -> the kernel is bound by per-CU shared pipes, dominated by LDS
// weight re-reads (76 ds_read_b128/wave-tile ~= 32 us/CU). Fix: process TILE
// PAIRS — each weight fragment is ds_read ONCE into a register and feeds TWO
// MFMAs (tile0/tile1 activations), halving ds_read/tile and doubling ILP per
// read. Register cost ~+60 -> back to the proven no-spill (512,2)/256-reg
// budget (8 waves/CU; occupancy proven irrelevant here).
// Wave wv owns 16 slots = 2 batches x 8 agents; slot s: a=s&7, bl=s>>3.
__global__ __launch_bounds__(512, 2)
void attention_critic_mfma(
    const float* __restrict__ states, const float* __restrict__ actions,
    const float* __restrict__ bs, const float* __restrict__ bv,
    const float* __restrict__ b1, const float* __restrict__ W2,
    const float* __restrict__ b2,
    const short* __restrict__ wts, float* __restrict__ out)
{
    __shared__ __align__(16) short smem[W_TOTAL];

    const int tid  = threadIdx.x;
    const int wv   = tid >> 6;       // wave 0..7
    const int lane = tid & 63;
    const int lq   = lane >> 4;
    const int ln   = lane & 15;

    // ---- stage all weights into LDS (76 x 1KiB chunks, global_load_lds w=16) ----
    for (int c = wv; c < 76; c += 8) {
        const unsigned int* g = reinterpret_cast<const unsigned int*>(wts + c * 512) + lane * 4;
        __builtin_amdgcn_global_load_lds(g, reinterpret_cast<unsigned int*>(smem + c * 512), 16, 0, 0);
    }

    // fragment-major per-lane base: fragment (s,lq,ch=nt*16+ln) lives at
    // short offset OFF + s*2048 + nt*128 + (lq*512 + ln*8)
    const int lo = lq * 512 + ln * 8;
    const short* lbA = smem + lo;             // We/Ws/Wk/Wsel
    const short* lbB = smem + OFF_Wv + lo;    // Wv/W1

    // per-lane bias / head-weight constants (cols of the respective C-layouts)
    float bS4[4], bv4[4], b14[4], w24[4];
    #pragma unroll
    for (int nt = 0; nt < 4; ++nt) {
        bS4[nt] = bs[nt * 16 + ln];
        bv4[nt] = bv[nt * 16 + ln];
        b14[nt] = b1[nt * 16 + ln];
        w24[nt] = W2[nt * 16 + ln];
    }
    const float b2v = b2[0];

    const int bbase = blockIdx.x * (PAIRS * 32);
    const int aA  = ln & 7;
    const int blA = ln >> 3;
    const float* srow = states  + ((long)aA * B_N + bbase + wv * 2 + blA) * S_N;
    const float* arow = actions + ((long)aA * B_N + bbase + wv * 2 + blA) * AD_N;

    __syncthreads();   // weights staged (drains vmcnt incl. global_load_lds)

    const floatx4 z = {0.f, 0.f, 0.f, 0.f};

    #pragma unroll 1
    for (int t = 0; t < PAIRS; ++t) {
        const int b0 = bbase + t * 32;

        // ---- load + convert both tiles' inputs (36 loads issued up front) ----
        short8 xf0[5], xf1[5];
        #pragma unroll
        for (int s = 0; s < 4; ++s) {
            float4 a0 = *reinterpret_cast<const float4*>(srow + s * 32 + lq * 8);
            float4 a1 = *reinterpret_cast<const float4*>(srow + s * 32 + lq * 8 + 4);
            float4 c0 = *reinterpret_cast<const float4*>(srow + 16 * S_N + s * 32 + lq * 8);
            float4 c1 = *reinterpret_cast<const float4*>(srow + 16 * S_N + s * 32 + lq * 8 + 4);
            xf0[s] = cvt8(a0, a1);
            xf1[s] = cvt8(c0, c1);
        }
        {
            short8 t0 = {0, 0, 0, 0, 0, 0, 0, 0}, t1 = t0;
            if (lq < 2) {
                float4 a0 = *reinterpret_cast<const float4*>(arow + lq * 8);
                float4 a1 = *reinterpret_cast<const float4*>(arow + lq * 8 + 4);
                float4 c0 = *reinterpret_cast<const float4*>(arow + 16 * AD_N + lq * 8);
                float4 c1 = *reinterpret_cast<const float4*>(arow + 16 * AD_N + lq * 8 + 4);
                t0 = cvt8(a0, a1);
                t1 = cvt8(c0, c1);
            } else if (lq == 2) {
                t0[0] = (short)0x3F80;   // bf16(1.0) at k=144 -> be bias row
                t1[0] = (short)0x3F80;
            }
            xf0[4] = t0; xf1[4] = t1;
        }
        srow += 32 * S_N; arow += 32 * AD_N;

        // ======== Phase 1a: E^T = We^T@X^T (paired), relu, pack ========
        short8 fE0[2], fE1[2];
        {
            floatx4 acc0[4] = {z, z, z, z}, acc1[4] = {z, z, z, z};
            #pragma unroll
            for (int s = 0; s < 5; ++s)
                #pragma unroll
                for (int nt = 0; nt < 4; ++nt) {
                    short8 wf = *reinterpret_cast<const short8*>(lbA + s * 2048 + nt * 128);
                    acc0[nt] = MFMA16(wf, xf0[s], acc0[nt]);
                    acc1[nt] = MFMA16(wf, xf1[s], acc1[nt]);
                }
            int p0[4][2], p1[4][2];
            #pragma unroll
            for (int nt = 0; nt < 4; ++nt) {
                p0[nt][0] = pk(fmaxf(acc0[nt][0], 0.f), fmaxf(acc0[nt][1], 0.f));
                p0[nt][1] = pk(fmaxf(acc0[nt][2], 0.f), fmaxf(acc0[nt][3], 0.f));
                p1[nt][0] = pk(fmaxf(acc1[nt][0], 0.f), fmaxf(acc1[nt][1], 0.f));
                p1[nt][1] = pk(fmaxf(acc1[nt][2], 0.f), fmaxf(acc1[nt][3], 0.f));
            }
            fE0[0] = mk8(p0[0][0], p0[0][1], p0[1][0], p0[1][1]);
            fE0[1] = mk8(p0[2][0], p0[2][1], p0[3][0], p0[3][1]);
            fE1[0] = mk8(p1[0][0], p1[0][1], p1[1][0], p1[1][1]);
            fE1[1] = mk8(p1[2][0], p1[2][1], p1[3][0], p1[3][1]);
        }
        SBAR();

        // ======== Phase 1b: S^T = Ws^T@X^T (K=128, paired), +bs, relu, pack ====
        short8 fS0[2], fS1[2];
        {
            floatx4 acc0[4] = {z, z, z, z}, acc1[4] = {z, z, z, z};
            #pragma unroll
            for (int s = 0; s < 4; ++s)
                #pragma unroll
                for (int nt = 0; nt < 4; ++nt) {
                    short8 wf = *reinterpret_cast<const short8*>(lbA + OFF_Ws + s * 2048 + nt * 128);
                    acc0[nt] = MFMA16(wf, xf0[s], acc0[nt]);
                    acc1[nt] = MFMA16(wf, xf1[s], acc1[nt]);
                }
            int p0[4][2], p1[4][2];
            #pragma unroll
            for (int nt = 0; nt < 4; ++nt) {
                p0[nt][0] = pk(fmaxf(acc0[nt][0] + bS4[nt], 0.f), fmaxf(acc0[nt][1] + bS4[nt], 0.f));
                p0[nt][1] = pk(fmaxf(acc0[nt][2] + bS4[nt], 0.f), fmaxf(acc0[nt][3] + bS4[nt], 0.f));
                p1[nt][0] = pk(fmaxf(acc1[nt][0] + bS4[nt], 0.f), fmaxf(acc1[nt][1] + bS4[nt], 0.f));
                p1[nt][1] = pk(fmaxf(acc1[nt][2] + bS4[nt], 0.f), fmaxf(acc1[nt][3] + bS4[nt], 0.f));
            }
            fS0[0] = mk8(p0[0][0], p0[0][1], p0[1][0], p0[1][1]);
            fS0[1] = mk8(p0[2][0], p0[2][1], p0[3][0], p0[3][1]);
            fS1[0] = mk8(p1[0][0], p1[0][1], p1[1][0], p1[1][1]);
            fS1[1] = mk8(p1[2][0], p1[2][1], p1[3][0], p1[3][1]);
        }
        SBAR();

        // ======== Phase 2a: K^T = Wk^T@E, Sel^T = Wsel^T@S (paired); pack ====
        int kp0[4][2], sp0[4][2], kp1[4][2], sp1[4][2];
        {
            floatx4 aK0[4] = {z, z, z, z}, aS0[4] = {z, z, z, z};
            floatx4 aK1[4] = {z, z, z, z}, aS1[4] = {z, z, z, z};
            #pragma unroll
            for (int s = 0; s < 2; ++s)
                #pragma unroll
                for (int nt = 0; nt < 4; ++nt) {
                    short8 wk = *reinterpret_cast<const short8*>(lbA + OFF_Wk   + s * 2048 + nt * 128);
                    short8 ws = *reinterpret_cast<const short8*>(lbA + OFF_Wsel + s * 2048 + nt * 128);
                    aK0[nt] = MFMA16(wk, fE0[s], aK0[nt]);
                    aK1[nt] = MFMA16(wk, fE1[s], aK1[nt]);
                    aS0[nt] = MFMA16(ws, fS0[s], aS0[nt]);
                    aS1[nt] = MFMA16(ws, fS1[s], aS1[nt]);
                }
            #pragma unroll
            for (int nt = 0; nt < 4; ++nt) {
                kp0[nt][0] = pk(aK0[nt][0], aK0[nt][1]); kp0[nt][1] = pk(aK0[nt][2], aK0[nt][3]);
                sp0[nt][0] = pk(aS0[nt][0], aS0[nt][1]); sp0[nt][1] = pk(aS0[nt][2], aS0[nt][3]);
                kp1[nt][0] = pk(aK1[nt][0], aK1[nt][1]); kp1[nt][1] = pk(aK1[nt][2], aK1[nt][3]);
                sp1[nt][0] = pk(aS1[nt][0], aS1[nt][1]); sp1[nt][1] = pk(aS1[nt][2], aS1[nt][3]);
            }
        }
        SBAR();

        // ======== Phase 2b: V = relu(E@Wv + bv) (paired); pack ========
        int pV0[4][2], pV1[4][2];
        {
            floatx4 a0[4] = {z, z, z, z}, a1[4] = {z, z, z, z};
            #pragma unroll
            for (int s = 0; s < 2; ++s)
                #pragma unroll
                for (int nt = 0; nt < 4; ++nt) {
                    short8 wf = *reinterpret_cast<const short8*>(lbB + s * 2048 + nt * 128);
                    a0[nt] = MFMA16(fE0[s], wf, a0[nt]);
                    a1[nt] = MFMA16(fE1[s], wf, a1[nt]);
                }
            #pragma unroll
            for (int nt = 0; nt < 4; ++nt) {
                pV0[nt][0] = pk(fmaxf(a0[nt][0] + bv4[nt], 0.f), fmaxf(a0[nt][1] + bv4[nt], 0.f));
                pV0[nt][1] = pk(fmaxf(a0[nt][2] + bv4[nt], 0.f), fmaxf(a0[nt][3] + bv4[nt], 0.f));
                pV1[nt][0] = pk(fmaxf(a1[nt][0] + bv4[nt], 0.f), fmaxf(a1[nt][1] + bv4[nt], 0.f));
                pV1[nt][1] = pk(fmaxf(a1[nt][2] + bv4[nt], 0.f), fmaxf(a1[nt][3] + bv4[nt], 0.f));
            }
        }
        SBAR();

        // ======== Phase 3: attention, fully in-register (both tiles) ========
        // L-MFMA (K=32, upper half zero): A = own-slot K (rows=j-slot=ln),
        // B = own-slot Sel (cols=i-slot=ln) -> L[j=4lq+i][i=ln].
        // Softmax over j = 4 regs + shfl_xor(16,32). PV-MFMA: A = V (rows=d=ln),
        // B = P -> other^T[d=4lq+i][slot=ln]. Cross-batch/self masked in P.
        int pO0[4][2], pO1[4][2];
        {
            const bool sameb = ((lq >> 1) == (ln >> 3));
            #pragma unroll
            for (int tt = 0; tt < 2; ++tt) {
                int (*kp)[2] = tt ? kp1 : kp0;
                int (*sp)[2] = tt ? sp1 : sp0;
                int (*pV)[2] = tt ? pV1 : pV0;
                int (*pO)[2] = tt ? pO1 : pO0;
                #pragma unroll
                for (int nt = 0; nt < 4; ++nt) {
                    short8 fa = mk8(kp[nt][0], kp[nt][1], 0, 0);
                    short8 fb = mk8(sp[nt][0], sp[nt][1], 0, 0);
                    floatx4 L = MFMA16(fa, fb, z);
                    float lg[4];
                    #pragma unroll
                    for (int i = 0; i < 4; ++i) {
                        const bool valid = sameb && (4 * lq + i != ln);
                        lg[i] = valid ? L[i] * 0.25f : -1e9f;   // 1/sqrt(16)
                    }
                    float m = fmaxf(fmaxf(lg[0], lg[1]), fmaxf(lg[2], lg[3]));
                    m = fmaxf(m, __shfl_xor(m, 16, 64));
                    m = fmaxf(m, __shfl_xor(m, 32, 64));
                    float e0 = __expf(lg[0] - m), e1 = __expf(lg[1] - m);
                    float e2 = __expf(lg[2] - m), e3 = __expf(lg[3] - m);
                    float ss = e0 + e1 + e2 + e3;
                    ss += __shfl_xor(ss, 16, 64);
                    ss += __shfl_xor(ss, 32, 64);
                    const float inv = 1.f / ss;
                    short8 fp = mk8(pk(e0 * inv, e1 * inv), pk(e2 * inv, e3 * inv), 0, 0);
                    short8 fv = mk8(pV[nt][0], pV[nt][1], 0, 0);
                    floatx4 O = MFMA16(fv, fp, z);
                    pO[nt][0] = pk(O[0], O[1]);
                    pO[nt][1] = pk(O[2], O[3]);
                }
            }
        }
        SBAR();

        // ======== Phase 4: h = relu([E|other]@W1+b1) ; q = h@W2 + b2 (paired) ==
        {
            short8 fO0[2] = { mk8(pO0[0][0], pO0[0][1], pO0[1][0], pO0[1][1]),
                              mk8(pO0[2][0], pO0[2][1], pO0[3][0], pO0[3][1]) };
            short8 fO1[2] = { mk8(pO1[0][0], pO1[0][1], pO1[1][0], pO1[1][1]),
                              mk8(pO1[2][0], pO1[2][1], pO1[3][0], pO1[3][1]) };
            floatx4 aH0[4] = {z, z, z, z}, aH1[4] = {z, z, z, z};
            #pragma unroll
            for (int s = 0; s < 4; ++s) {
                const short8 a0 = (s < 2) ? fE0[s] : fO0[s - 2];
                const short8 a1 = (s < 2) ? fE1[s] : fO1[s - 2];
                #pragma unroll
                for (int nt = 0; nt < 4; ++nt) {
                    short8 w1 = *reinterpret_cast<const short8*>(lbB + 4096 + s * 2048 + nt * 128);
                    aH0[nt] = MFMA16(a0, w1, aH0[nt]);
                    aH1[nt] = MFMA16(a1, w1, aH1[nt]);
                }
            }
            #pragma unroll
            for (int tt = 0; tt < 2; ++tt) {
                floatx4* aH = tt ? aH1 : aH0;
                float p0 = 0.f, p1 = 0.f, p2 = 0.f, p3 = 0.f;
                #pragma unroll
                for (int nt = 0; nt < 4; ++nt) {
                    p0 += fmaxf(aH[nt][0] + b14[nt], 0.f) * w24[nt];
                    p1 += fmaxf(aH[nt][1] + b14[nt], 0.f) * w24[nt];
                    p2 += fmaxf(aH[nt][2] + b14[nt], 0.f) * w24[nt];
                    p3 += fmaxf(aH[nt][3] + b14[nt], 0.f) * w24[nt];
                }
                #pragma unroll
                for (int mk = 1; mk < 16; mk <<= 1) {
                    p0 += __shfl_xor(p0, mk, 64);
                    p1 += __shfl_xor(p1, mk, 64);
                    p2 += __shfl_xor(p2, mk, 64);
                    p3 += __shfl_xor(p3, mk, 64);
                }
                if (ln == 0) {
                    float pr[4] = {p0, p1, p2, p3};
                    const int bt = b0 + tt * 16;
                    #pragma unroll
                    for (int i = 0; i < 4; ++i) {
                        const int slot = lq * 4 + i;   // slot -> (a=slot&7, bl=slot>>3)
                        out[(long)(slot & 7) * B_N + bt + wv * 2 + (slot >> 3)] = pr[i] + b2v;
                    }
                }
            }
        }
        SBAR();   // keep next pair's loads/compute out of this region
        // no barriers in the loop: everything wave/lane-local; waves free-run
    }
}

extern "C" void kernel_launch(void* const* d_in, const int* in_sizes, int n_in,
                              void* d_out, int out_size, void* d_ws, size_t ws_size,
                              hipStream_t stream) {
    const float* states  = (const float*)d_in[0];
    const float* actions = (const float*)d_in[1];
    const float* Ws      = (const float*)d_in[2];
    const float* bs      = (const float*)d_in[3];
    const float* We      = (const float*)d_in[4];
    const float* be      = (const float*)d_in[5];
    const float* Wk      = (const float*)d_in[6];
    const float* Wsel    = (const float*)d_in[7];
    const float* Wv      = (const float*)d_in[8];
    const float* bv      = (const float*)d_in[9];
    const float* W1      = (const float*)d_in[10];
    const float* b1      = (const float*)d_in[11];
    const float* W2      = (const float*)d_in[12];
    const float* b2      = (const float*)d_in[13];
    short* wts = (short*)d_ws;
    float* out = (float*)d_out;

    prep_weights<<<(W_TOTAL + 255) / 256, 256, 0, stream>>>(Ws, We, be, Wk, Wsel, Wv, W1, wts);
    attention_critic_mfma<<<B_N / (PAIRS * 32), 512, 0, stream>>>(
        states, actions, bs, bv, b1, W2, b2, wts, out);
}